// Round 2
// baseline (542.116 us; speedup 1.0000x reference)
//
#include <hip/hip_runtime.h>
#include <stdint.h>

typedef unsigned short ushort_t;
typedef __attribute__((ext_vector_type(8))) short short8;
typedef __attribute__((ext_vector_type(4))) float f32x4;

#define AS1 __attribute__((address_space(1)))
#define AS3 __attribute__((address_space(3)))

// async global->LDS, 16B per lane; LDS dest is wave-uniform base + lane*16
__device__ __forceinline__ void gl_lds16(const void* g, void* l) {
    __builtin_amdgcn_global_load_lds((const AS1 unsigned int*)g,
                                     (AS3 unsigned int*)l, 16, 0, 0);
}

__device__ __forceinline__ ushort_t f2bf(float f) {   // RNE f32 -> bf16
    union { float f; unsigned u; } v; v.f = f;
    unsigned r = v.u + 0x7fffu + ((v.u >> 16) & 1u);
    return (ushort_t)(r >> 16);
}

// ---------------------------------------------------------------------------
// Kernel 0: f32 -> bf16 convert (RNE), 8 elements/thread
// ---------------------------------------------------------------------------
__global__ __launch_bounds__(256) void cvt_k(const float* __restrict__ src,
                                             ushort_t* __restrict__ dst, int n) {
    int i = (blockIdx.x * 256 + threadIdx.x) * 8;
    if (i >= n) return;
    float4 a = *(const float4*)(src + i);
    float4 b = *(const float4*)(src + i + 4);
    short8 o;
    o[0] = (short)f2bf(a.x); o[1] = (short)f2bf(a.y);
    o[2] = (short)f2bf(a.z); o[3] = (short)f2bf(a.w);
    o[4] = (short)f2bf(b.x); o[5] = (short)f2bf(b.y);
    o[6] = (short)f2bf(b.z); o[7] = (short)f2bf(b.w);
    *(short8*)(dst + i) = o;
}

// ---------------------------------------------------------------------------
// Kernel 1: transpose+convert Wq/Wk/Wv (f32) [16][1024][64] -> WT bf16 [3][16][64][1024]
// ---------------------------------------------------------------------------
__global__ __launch_bounds__(256) void wtrans_k(const float* Wq, const float* Wk,
                                                const float* Wv, ushort_t* WT) {
    __shared__ ushort_t t[64 * 65];
    const int bx = blockIdx.x;            // 0..767 : mat(3) x h(16) x etile(16)
    const int mat = bx >> 8;
    const int h   = (bx >> 4) & 15;
    const int et  = bx & 15;
    const float* W = (mat == 0 ? Wq : (mat == 1 ? Wk : Wv)) + h * (1024 * 64);
    const float* src = W + et * 64 * 64;   // rows e0..e0+63 contiguous
    const int tid = threadIdx.x;
#pragma unroll
    for (int i = 0; i < 16; ++i) {
        int idx = i * 256 + tid;              // 0..4095
        int e = idx >> 6, d = idx & 63;
        t[e * 65 + d] = f2bf(src[idx]);
    }
    __syncthreads();
    ushort_t* dst = WT + (mat * 16 + h) * (64 * 1024) + et * 64;
#pragma unroll
    for (int i = 0; i < 16; ++i) {
        int idx = i * 256 + tid;
        int d = idx >> 6, e = idx & 63;
        dst[d * 1024 + e] = t[e * 65 + d];
    }
}

// ---------------------------------------------------------------------------
// Kernel 2: QKV projection. C[8192x64] = inp_bf[8192x1024] * W_h[1024x64]
// gemm_bt: BT = WT[mat][h] is [64][1024] (K-contiguous).
// Block tile 256(M) x 64(N), 4 waves stacked in M, each wave 64x64 (4x4 frags).
// ---------------------------------------------------------------------------
__global__ __launch_bounds__(256) void qkv_k(const ushort_t* A, const ushort_t* WT,
                                             ushort_t* Q, ushort_t* K, ushort_t* V) {
    __shared__ __align__(16) ushort_t As[256 * 64];   // 32 KB
    __shared__ __align__(16) ushort_t Bs[64 * 64];    //  8 KB
    const int tid = threadIdx.x, wave = tid >> 6, lane = tid & 63;
    const int ln15 = lane & 15, quad = lane >> 4;
    const int lrow = lane >> 3, lcol = (lane & 7) * 8;
    const int m0 = blockIdx.x * 256;
    const int mh = blockIdx.y;                         // mat*16 + h
    const ushort_t* BT = WT + (size_t)mh * (64 * 1024);

    f32x4 acc[4][4];
#pragma unroll
    for (int i = 0; i < 4; ++i)
#pragma unroll
        for (int j = 0; j < 4; ++j)
#pragma unroll
            for (int e = 0; e < 4; ++e) acc[i][j][e] = 0.f;

    for (int k0 = 0; k0 < 1024; k0 += 64) {
        __syncthreads();
#pragma unroll
        for (int i = 0; i < 8; ++i) {
            int br = i * 32 + wave * 8;
            gl_lds16(A + (size_t)(m0 + br + lrow) * 1024 + k0 + lcol, &As[br * 64]);
        }
#pragma unroll
        for (int i = 0; i < 2; ++i) {
            int br = i * 32 + wave * 8;
            gl_lds16(BT + (size_t)(br + lrow) * 1024 + k0 + lcol, &Bs[br * 64]);
        }
        __syncthreads();
#pragma unroll
        for (int kk = 0; kk < 2; ++kk) {
            short8 a[4], b[4];
#pragma unroll
            for (int f = 0; f < 4; ++f)
                a[f] = *(const short8*)&As[(wave * 64 + f * 16 + ln15) * 64 + kk * 32 + quad * 8];
#pragma unroll
            for (int f = 0; f < 4; ++f)
                b[f] = *(const short8*)&Bs[(f * 16 + ln15) * 64 + kk * 32 + quad * 8];
#pragma unroll
            for (int fm = 0; fm < 4; ++fm)
#pragma unroll
                for (int fn = 0; fn < 4; ++fn)
                    acc[fm][fn] = __builtin_amdgcn_mfma_f32_16x16x32_bf16(a[fm], b[fn], acc[fm][fn], 0, 0, 0);
        }
    }
    const int mat = mh >> 4, h = mh & 15;
    ushort_t* dst = (mat == 0) ? Q : (mat == 1 ? K : V);
    const float scale = (mat == 0) ? 0.125f : 1.0f;   // 1/sqrt(64) folded into Q
#pragma unroll
    for (int fm = 0; fm < 4; ++fm) {
#pragma unroll
        for (int r = 0; r < 4; ++r) {
            int mg = m0 + wave * 64 + fm * 16 + quad * 4 + r;
            int bi = mg >> 11, s = mg & 2047;
            size_t base = ((size_t)(bi * 16 + h) * 2048 + s) * 64;
#pragma unroll
            for (int fn = 0; fn < 4; ++fn)
                dst[base + fn * 16 + ln15] = f2bf(acc[fm][fn][r] * scale);
        }
    }
}

// ---------------------------------------------------------------------------
// Kernel 3: causal flash attention. One block = (b,h) x 64 q-rows.
// 4 waves, each owns 16 q-rows. 64-key tiles, online softmax.
// ---------------------------------------------------------------------------
__global__ __launch_bounds__(256) void flash_k(const ushort_t* Q, const ushort_t* K,
                                               const ushort_t* V, ushort_t* Aout) {
    __shared__ __align__(16) ushort_t Qs[64 * 64];    // 8 KB (no pad: global_load_lds)
    __shared__ __align__(16) ushort_t Ks[64 * 64];    // 8 KB
    __shared__ __align__(16) ushort_t Vt[64 * 72];    // V^T, padded (+8)
    __shared__ __align__(16) ushort_t Ps[4 * 16 * 72];// per-wave P, padded
    const int tid = threadIdx.x, wave = tid >> 6, lane = tid & 63;
    const int ln15 = lane & 15, quad = lane >> 4;
    const int lrow = lane >> 3, lcol = (lane & 7) * 8;
    const int qt = blockIdx.x;                 // q-tile (32)
    const int bh = blockIdx.y;                 // b*16+h (64)
    const int q0 = qt * 64;
    const ushort_t* Qb = Q + ((size_t)bh * 2048 + q0) * 64;
    const ushort_t* Kb = K + (size_t)bh * 2048 * 64;
    const ushort_t* Vb = V + (size_t)bh * 2048 * 64;

#pragma unroll
    for (int i = 0; i < 2; ++i) {
        int br = i * 32 + wave * 8;
        gl_lds16(Qb + (size_t)(br + lrow) * 64 + lcol, &Qs[br * 64]);
    }
    __syncthreads();
    short8 qa0 = *(const short8*)&Qs[(wave * 16 + ln15) * 64 + quad * 8];
    short8 qa1 = *(const short8*)&Qs[(wave * 16 + ln15) * 64 + 32 + quad * 8];

    f32x4 o[4];
#pragma unroll
    for (int nt = 0; nt < 4; ++nt)
#pragma unroll
        for (int e = 0; e < 4; ++e) o[nt][e] = 0.f;
    float m_r[4], l_r[4];
#pragma unroll
    for (int r = 0; r < 4; ++r) { m_r[r] = -1e30f; l_r[r] = 0.f; }

    for (int kt = 0; kt <= qt; ++kt) {
        __syncthreads();   // previous iteration's reads of Ks/Vt done
#pragma unroll
        for (int i = 0; i < 2; ++i) {
            int br = i * 32 + wave * 8;
            gl_lds16(Kb + (size_t)(kt * 64 + br + lrow) * 64 + lcol, &Ks[br * 64]);
        }
        // stage V transposed: Vt[d][key]
#pragma unroll
        for (int it = 0; it < 2; ++it) {
            int key = it * 32 + (tid >> 3);
            int c8 = (tid & 7) * 8;
            short8 v = *(const short8*)&Vb[(size_t)(kt * 64 + key) * 64 + c8];
#pragma unroll
            for (int j = 0; j < 8; ++j) Vt[(c8 + j) * 72 + key] = (ushort_t)v[j];
        }
        __syncthreads();

        // S = Q K^T  (C: col=key(ln15), row=quad*4+r)
        f32x4 sc[4];
#pragma unroll
        for (int nt = 0; nt < 4; ++nt) {
            f32x4 z;
#pragma unroll
            for (int e = 0; e < 4; ++e) z[e] = 0.f;
            short8 kb = *(const short8*)&Ks[(nt * 16 + ln15) * 64 + quad * 8];
            sc[nt] = __builtin_amdgcn_mfma_f32_16x16x32_bf16(qa0, kb, z, 0, 0, 0);
            kb = *(const short8*)&Ks[(nt * 16 + ln15) * 64 + 32 + quad * 8];
            sc[nt] = __builtin_amdgcn_mfma_f32_16x16x32_bf16(qa1, kb, sc[nt], 0, 0, 0);
        }
        if (kt == qt) {   // diagonal tile: causal mask
#pragma unroll
            for (int nt = 0; nt < 4; ++nt) {
                int kg = kt * 64 + nt * 16 + ln15;
#pragma unroll
                for (int r = 0; r < 4; ++r) {
                    int qg = q0 + wave * 16 + quad * 4 + r;
                    if (kg > qg) sc[nt][r] = -1e30f;
                }
            }
        }
        // online softmax, per C-row (quad*4+r); reduce across the 16 lanes of the quad group
#pragma unroll
        for (int r = 0; r < 4; ++r) {
            float mx = fmaxf(fmaxf(sc[0][r], sc[1][r]), fmaxf(sc[2][r], sc[3][r]));
            mx = fmaxf(mx, __shfl_xor(mx, 1));
            mx = fmaxf(mx, __shfl_xor(mx, 2));
            mx = fmaxf(mx, __shfl_xor(mx, 4));
            mx = fmaxf(mx, __shfl_xor(mx, 8));
            float mnew = fmaxf(m_r[r], mx);
            float alpha = __expf(m_r[r] - mnew);
            float sum = 0.f;
#pragma unroll
            for (int nt = 0; nt < 4; ++nt) {
                float p = __expf(sc[nt][r] - mnew);
                sc[nt][r] = p; sum += p;
            }
            sum += __shfl_xor(sum, 1);
            sum += __shfl_xor(sum, 2);
            sum += __shfl_xor(sum, 4);
            sum += __shfl_xor(sum, 8);
            l_r[r] = l_r[r] * alpha + sum;
            m_r[r] = mnew;
#pragma unroll
            for (int nt = 0; nt < 4; ++nt) o[nt][r] *= alpha;
#pragma unroll
            for (int nt = 0; nt < 4; ++nt)
                Ps[(wave * 16 + quad * 4 + r) * 72 + nt * 16 + ln15] = f2bf(sc[nt][r]);
        }
        // P: C-layout -> A-layout via per-wave LDS (same-wave ds ops are in order)
        short8 pa0 = *(const short8*)&Ps[(wave * 16 + ln15) * 72 + quad * 8];
        short8 pa1 = *(const short8*)&Ps[(wave * 16 + ln15) * 72 + 32 + quad * 8];
#pragma unroll
        for (int nt = 0; nt < 4; ++nt) {
            short8 vb = *(const short8*)&Vt[(nt * 16 + ln15) * 72 + quad * 8];
            o[nt] = __builtin_amdgcn_mfma_f32_16x16x32_bf16(pa0, vb, o[nt], 0, 0, 0);
            vb = *(const short8*)&Vt[(nt * 16 + ln15) * 72 + 32 + quad * 8];
            o[nt] = __builtin_amdgcn_mfma_f32_16x16x32_bf16(pa1, vb, o[nt], 0, 0, 0);
        }
    }
    // epilogue: attn[b][s][h*64+d] (bf16)
    const int bi = bh >> 4, h = bh & 15;
#pragma unroll
    for (int r = 0; r < 4; ++r) {
        float inv = 1.f / l_r[r];
        int qg = q0 + wave * 16 + quad * 4 + r;
        size_t base = ((size_t)bi * 2048 + qg) * 1024 + h * 64;
#pragma unroll
        for (int nt = 0; nt < 4; ++nt)
            Aout[base + nt * 16 + ln15] = f2bf(o[nt][r] * inv);
    }
}

// ---------------------------------------------------------------------------
// Kernel 4: out(f32) = attn_bf[8192x1024] * WoB^T + bo(f32).
// BT = WoB natural (row-major [n][k]). m97-style 128x128 tile, 4 waves 2x2.
// ---------------------------------------------------------------------------
__global__ __launch_bounds__(256) void outproj_k(const ushort_t* A, const ushort_t* WoB,
                                                 const float* bo, float* Out) {
    __shared__ __align__(16) ushort_t As[128 * 64];   // 16 KB
    __shared__ __align__(16) ushort_t Bs[128 * 64];   // 16 KB
    const int tid = threadIdx.x, wave = tid >> 6, lane = tid & 63;
    const int ln15 = lane & 15, quad = lane >> 4;
    const int wm = wave >> 1, wn = wave & 1;
    const int lrow = lane >> 3, lcol = (lane & 7) * 8;
    const int m0 = blockIdx.x * 128, n0 = blockIdx.y * 128;

    f32x4 acc[4][4];
#pragma unroll
    for (int i = 0; i < 4; ++i)
#pragma unroll
        for (int j = 0; j < 4; ++j)
#pragma unroll
            for (int e = 0; e < 4; ++e) acc[i][j][e] = 0.f;

    for (int k0 = 0; k0 < 1024; k0 += 64) {
        __syncthreads();
#pragma unroll
        for (int i = 0; i < 4; ++i) {
            int br = i * 32 + wave * 8;
            gl_lds16(A   + (size_t)(m0 + br + lrow) * 1024 + k0 + lcol, &As[br * 64]);
            gl_lds16(WoB + (size_t)(n0 + br + lrow) * 1024 + k0 + lcol, &Bs[br * 64]);
        }
        __syncthreads();
#pragma unroll
        for (int kk = 0; kk < 2; ++kk) {
            short8 a[4], b[4];
#pragma unroll
            for (int f = 0; f < 4; ++f)
                a[f] = *(const short8*)&As[(wm * 64 + f * 16 + ln15) * 64 + kk * 32 + quad * 8];
#pragma unroll
            for (int f = 0; f < 4; ++f)
                b[f] = *(const short8*)&Bs[(wn * 64 + f * 16 + ln15) * 64 + kk * 32 + quad * 8];
#pragma unroll
            for (int fm = 0; fm < 4; ++fm)
#pragma unroll
                for (int fn = 0; fn < 4; ++fn)
                    acc[fm][fn] = __builtin_amdgcn_mfma_f32_16x16x32_bf16(a[fm], b[fn], acc[fm][fn], 0, 0, 0);
        }
    }
#pragma unroll
    for (int fn = 0; fn < 4; ++fn) {
        int n = n0 + wn * 64 + fn * 16 + ln15;
        float bias = bo[n];
#pragma unroll
        for (int fm = 0; fm < 4; ++fm)
#pragma unroll
            for (int r = 0; r < 4; ++r) {
                int mg = m0 + wm * 64 + fm * 16 + quad * 4 + r;
                Out[(size_t)mg * 1024 + n] = acc[fm][fn][r] + bias;
            }
    }
}

// ---------------------------------------------------------------------------
extern "C" void kernel_launch(void* const* d_in, const int* in_sizes, int n_in,
                              void* d_out, int out_size, void* d_ws, size_t ws_size,
                              hipStream_t stream) {
    (void)in_sizes; (void)n_in; (void)out_size; (void)ws_size;
    const float* inp = (const float*)d_in[0];   // [4,2048,1024] f32
    const float* Wq  = (const float*)d_in[1];   // [16,1024,64]  f32
    const float* Wk  = (const float*)d_in[2];
    const float* Wv  = (const float*)d_in[3];
    const float* Wo  = (const float*)d_in[4];   // [1024,1024]   f32
    const float* bo  = (const float*)d_in[5];   // [1024]        f32
    float* out = (float*)d_out;                  // [4,2048,1024] f32

    ushort_t* ws = (ushort_t*)d_ws;
    // R0 (16 MB): inp_bf during kernels 0-2, then At during kernels 3-4
    ushort_t* R0  = ws;                       // 8,388,608 el
    ushort_t* WT  = R0  + 8388608;            // [3][16][64][1024] = 3,145,728 el
    ushort_t* WoB = WT  + 3145728;            // [1024][1024]      = 1,048,576 el
    ushort_t* Qb  = WoB + 1048576;            // [4][16][2048][64] = 8,388,608 el
    ushort_t* Kb  = Qb  + 8388608;
    ushort_t* Vb  = Kb  + 8388608;
    // total ws: 37,748,736 ushorts = 75.5 MB

    ushort_t* inp_bf = R0;
    ushort_t* At     = R0;

    cvt_k<<<4096, 256, 0, stream>>>(inp, inp_bf, 8388608);
    cvt_k<<<512, 256, 0, stream>>>(Wo, WoB, 1048576);
    wtrans_k<<<768, 256, 0, stream>>>(Wq, Wk, Wv, WT);
    qkv_k<<<dim3(32, 48), 256, 0, stream>>>(inp_bf, WT, Qb, Kb, Vb);
    flash_k<<<dim3(32, 64), 256, 0, stream>>>(Qb, Kb, Vb, At);
    outproj_k<<<dim3(64, 8), 256, 0, stream>>>(At, Wo != nullptr ? WoB : WoB, bo, out);
}

// Round 4
// 283.069 us; speedup vs baseline: 1.9151x; 1.9151x over previous
//
#include <hip/hip_runtime.h>
#include <stdint.h>

typedef unsigned short ushort_t;
typedef __attribute__((ext_vector_type(8))) short short8;
typedef __attribute__((ext_vector_type(4))) short bf16x4;
typedef __attribute__((ext_vector_type(4))) float f32x4;

#define AS1 __attribute__((address_space(1)))
#define AS3 __attribute__((address_space(3)))

// async global->LDS, 16B per lane; LDS dest is wave-uniform base + lane*16
__device__ __forceinline__ void gl_lds16(const void* g, void* l) {
    __builtin_amdgcn_global_load_lds((const AS1 unsigned int*)g,
                                     (AS3 unsigned int*)l, 16, 0, 0);
}

__device__ __forceinline__ ushort_t f2bf(float f) {   // RNE f32 -> bf16
    union { float f; unsigned u; } v; v.f = f;
    unsigned r = v.u + 0x7fffu + ((v.u >> 16) & 1u);
    return (ushort_t)(r >> 16);
}

// ---------------------------------------------------------------------------
// Kernel 0: f32 -> bf16 convert (RNE), 8 elements/thread
// ---------------------------------------------------------------------------
__global__ __launch_bounds__(256) void cvt_k(const float* __restrict__ src,
                                             ushort_t* __restrict__ dst, int n) {
    int i = (blockIdx.x * 256 + threadIdx.x) * 8;
    if (i >= n) return;
    float4 a = *(const float4*)(src + i);
    float4 b = *(const float4*)(src + i + 4);
    short8 o;
    o[0] = (short)f2bf(a.x); o[1] = (short)f2bf(a.y);
    o[2] = (short)f2bf(a.z); o[3] = (short)f2bf(a.w);
    o[4] = (short)f2bf(b.x); o[5] = (short)f2bf(b.y);
    o[6] = (short)f2bf(b.z); o[7] = (short)f2bf(b.w);
    *(short8*)(dst + i) = o;
}

// ---------------------------------------------------------------------------
// Kernel 1: transpose+convert Wq/Wk/Wv (f32) [16][1024][64] -> WT bf16 [3][16][64][1024]
// ---------------------------------------------------------------------------
__global__ __launch_bounds__(256) void wtrans_k(const float* Wq, const float* Wk,
                                                const float* Wv, ushort_t* WT) {
    __shared__ ushort_t t[64 * 65];
    const int bx = blockIdx.x;            // 0..767 : mat(3) x h(16) x etile(16)
    const int mat = bx >> 8;
    const int h   = (bx >> 4) & 15;
    const int et  = bx & 15;
    const float* W = (mat == 0 ? Wq : (mat == 1 ? Wk : Wv)) + h * (1024 * 64);
    const float* src = W + et * 64 * 64;
    const int tid = threadIdx.x;
#pragma unroll
    for (int i = 0; i < 16; ++i) {
        int idx = i * 256 + tid;
        int e = idx >> 6, d = idx & 63;
        t[e * 65 + d] = f2bf(src[idx]);
    }
    __syncthreads();
    ushort_t* dst = WT + (mat * 16 + h) * (64 * 1024) + et * 64;
#pragma unroll
    for (int i = 0; i < 16; ++i) {
        int idx = i * 256 + tid;
        int d = idx >> 6, e = idx & 63;
        dst[d * 1024 + e] = t[e * 65 + d];
    }
}

// ---------------------------------------------------------------------------
// Kernel 2: QKV projection. C[8192x64] = inp_bf[8192x1024] * W_h[1024x64]
// Q,K written [B,H,S,64]; V written TRANSPOSED [B,H,64,S] (flash needs V^T;
// scattered 2B stores are L2-write-combined — cheaper than per-tile LDS transpose).
// ---------------------------------------------------------------------------
__global__ __launch_bounds__(256) void qkv_k(const ushort_t* A, const ushort_t* WT,
                                             ushort_t* Q, ushort_t* K, ushort_t* Vt) {
    __shared__ __align__(16) ushort_t As[256 * 64];   // 32 KB
    __shared__ __align__(16) ushort_t Bs[64 * 64];    //  8 KB
    const int tid = threadIdx.x, wave = tid >> 6, lane = tid & 63;
    const int ln15 = lane & 15, quad = lane >> 4;
    const int lrow = lane >> 3, lcol = (lane & 7) * 8;
    const int m0 = blockIdx.x * 256;
    const int mh = blockIdx.y;                         // mat*16 + h
    const ushort_t* BT = WT + (size_t)mh * (64 * 1024);

    f32x4 acc[4][4];
#pragma unroll
    for (int i = 0; i < 4; ++i)
#pragma unroll
        for (int j = 0; j < 4; ++j)
#pragma unroll
            for (int e = 0; e < 4; ++e) acc[i][j][e] = 0.f;

    for (int k0 = 0; k0 < 1024; k0 += 64) {
        __syncthreads();
#pragma unroll
        for (int i = 0; i < 8; ++i) {
            int br = i * 32 + wave * 8;
            gl_lds16(A + (size_t)(m0 + br + lrow) * 1024 + k0 + lcol, &As[br * 64]);
        }
#pragma unroll
        for (int i = 0; i < 2; ++i) {
            int br = i * 32 + wave * 8;
            gl_lds16(BT + (size_t)(br + lrow) * 1024 + k0 + lcol, &Bs[br * 64]);
        }
        __syncthreads();
#pragma unroll
        for (int kk = 0; kk < 2; ++kk) {
            short8 a[4], b[4];
#pragma unroll
            for (int f = 0; f < 4; ++f)
                a[f] = *(const short8*)&As[(wave * 64 + f * 16 + ln15) * 64 + kk * 32 + quad * 8];
#pragma unroll
            for (int f = 0; f < 4; ++f)
                b[f] = *(const short8*)&Bs[(f * 16 + ln15) * 64 + kk * 32 + quad * 8];
#pragma unroll
            for (int fm = 0; fm < 4; ++fm)
#pragma unroll
                for (int fn = 0; fn < 4; ++fn)
                    acc[fm][fn] = __builtin_amdgcn_mfma_f32_16x16x32_bf16(a[fm], b[fn], acc[fm][fn], 0, 0, 0);
        }
    }
    const int mat = mh >> 4, h = mh & 15;
    if (mat < 2) {
        ushort_t* dst = (mat == 0) ? Q : K;
        const float scale = (mat == 0) ? 0.125f : 1.0f;   // 1/sqrt(64) folded into Q
#pragma unroll
        for (int fm = 0; fm < 4; ++fm) {
#pragma unroll
            for (int r = 0; r < 4; ++r) {
                int mg = m0 + wave * 64 + fm * 16 + quad * 4 + r;
                int bi = mg >> 11, s = mg & 2047;
                size_t base = ((size_t)(bi * 16 + h) * 2048 + s) * 64;
#pragma unroll
                for (int fn = 0; fn < 4; ++fn)
                    dst[base + fn * 16 + ln15] = f2bf(acc[fm][fn][r] * scale);
            }
        }
    } else {
        // V transposed: Vt[b][h][d][s]
#pragma unroll
        for (int fm = 0; fm < 4; ++fm) {
#pragma unroll
            for (int r = 0; r < 4; ++r) {
                int mg = m0 + wave * 64 + fm * 16 + quad * 4 + r;
                int bi = mg >> 11, s = mg & 2047;
#pragma unroll
                for (int fn = 0; fn < 4; ++fn) {
                    int d = fn * 16 + ln15;
                    Vt[((size_t)(bi * 16 + h) * 64 + d) * 2048 + s] = f2bf(acc[fm][fn][r]);
                }
            }
        }
    }
}

// ---------------------------------------------------------------------------
// Kernel 3: causal flash attention, S^T formulation.
// Block = 4 waves, q-tile 128 (32 q/wave). Per 64-key tile:
//   S^T = K·Q^T (C: row=key=quad*4+r, col=q=ln15) -> softmax state is per-lane
//   (2 shfls instead of 32), P^T packed to LDS via b64, O^T = V^T·P^T.
// Grid ordered big-qt-first for load balance; fully-masked waves skip compute.
// ---------------------------------------------------------------------------
__global__ __launch_bounds__(256, 3) void flash_k(const ushort_t* Q, const ushort_t* K,
                                                  const ushort_t* Vt, ushort_t* Aout) {
    __shared__ __align__(16) ushort_t Qs[128 * 64];    // 16 KB
    __shared__ __align__(16) ushort_t Ks[64 * 64];     //  8 KB
    __shared__ __align__(16) ushort_t Vts[64 * 64];    //  8 KB
    __shared__ __align__(16) ushort_t PT[4][32 * 72];  // 18 KB, per-wave P^T[q][key]
    const int tid = threadIdx.x, wave = tid >> 6, lane = tid & 63;
    const int ln15 = lane & 15, quad = lane >> 4;
    const int bx = blockIdx.x;
    const int qt = 15 - (bx >> 6);             // big tiles dispatch first
    const int bh = bx & 63;
    const int q0 = qt * 128;
    const int qw = q0 + wave * 32;             // this wave's first q row
    const ushort_t* Qb = Q + ((size_t)bh * 2048 + q0) * 64;
    const ushort_t* Kb = K + (size_t)bh * 2048 * 64;
    const ushort_t* Vb = Vt + (size_t)bh * 64 * 2048;
    ushort_t* myPT = PT[wave];

    // stage Q tile 128x64
    {
        int c8 = (tid & 7) * 8;
#pragma unroll
        for (int i = 0; i < 4; ++i) {
            int row = i * 32 + (tid >> 3);
            gl_lds16(Qb + (size_t)row * 64 + c8, &Qs[row * 64 + c8]);
        }
    }
    __syncthreads();
    short8 qf[2][2];
#pragma unroll
    for (int qs = 0; qs < 2; ++qs)
#pragma unroll
        for (int kk = 0; kk < 2; ++kk)
            qf[qs][kk] = *(const short8*)&Qs[(wave * 32 + qs * 16 + ln15) * 64 + kk * 32 + quad * 8];

    f32x4 o[4][2];
#pragma unroll
    for (int dt = 0; dt < 4; ++dt)
#pragma unroll
        for (int qs = 0; qs < 2; ++qs)
#pragma unroll
            for (int e = 0; e < 4; ++e) o[dt][qs][e] = 0.f;
    float m_s[2] = {-1e30f, -1e30f}, l_s[2] = {0.f, 0.f};

    const int ktEnd = 2 * qt + 2;
    for (int kt = 0; kt < ktEnd; ++kt) {
        __syncthreads();   // prior reads of Ks/Vts complete
        {
            int row = tid >> 3, c8 = (tid & 7) * 8;
            gl_lds16(Kb + (size_t)(kt * 64 + row) * 64 + c8,      &Ks[row * 64 + c8]);
            gl_lds16(Kb + (size_t)(kt * 64 + 32 + row) * 64 + c8, &Ks[(32 + row) * 64 + c8]);
            gl_lds16(Vb + (size_t)row * 2048 + kt * 64 + c8,        &Vts[row * 64 + c8]);
            gl_lds16(Vb + (size_t)(32 + row) * 2048 + kt * 64 + c8, &Vts[(32 + row) * 64 + c8]);
        }
        __syncthreads();
        if (kt * 64 > qw + 31) continue;       // wave fully masked (uniform)

        // S^T = K . Q^T
        f32x4 sc[4][2];
#pragma unroll
        for (int ks = 0; ks < 4; ++ks) {
#pragma unroll
            for (int qs = 0; qs < 2; ++qs)
#pragma unroll
                for (int e = 0; e < 4; ++e) sc[ks][qs][e] = 0.f;
#pragma unroll
            for (int kk = 0; kk < 2; ++kk) {
                short8 kf = *(const short8*)&Ks[(ks * 16 + ln15) * 64 + kk * 32 + quad * 8];
#pragma unroll
                for (int qs = 0; qs < 2; ++qs)
                    sc[ks][qs] = __builtin_amdgcn_mfma_f32_16x16x32_bf16(kf, qf[qs][kk], sc[ks][qs], 0, 0, 0);
            }
        }
        if (kt * 64 + 63 > qw) {               // diagonal: causal mask
#pragma unroll
            for (int ks = 0; ks < 4; ++ks)
#pragma unroll
                for (int qs = 0; qs < 2; ++qs) {
                    int qg = qw + qs * 16 + ln15;
#pragma unroll
                    for (int r = 0; r < 4; ++r) {
                        int kg = kt * 64 + ks * 16 + quad * 4 + r;
                        if (kg > qg) sc[ks][qs][r] = -1e30f;
                    }
                }
        }
        // online softmax: per-lane state (col q = ln15), reduce across quads only
#pragma unroll
        for (int qs = 0; qs < 2; ++qs) {
            float mx = sc[0][qs][0];
#pragma unroll
            for (int ks = 0; ks < 4; ++ks)
#pragma unroll
                for (int r = 0; r < 4; ++r) mx = fmaxf(mx, sc[ks][qs][r]);
            mx = fmaxf(mx, __shfl_xor(mx, 16));
            mx = fmaxf(mx, __shfl_xor(mx, 32));
            float mnew = fmaxf(m_s[qs], mx);
            float alpha = __expf(m_s[qs] - mnew);
            float sum = 0.f;
#pragma unroll
            for (int ks = 0; ks < 4; ++ks) {
                bf16x4 pk;
#pragma unroll
                for (int r = 0; r < 4; ++r) {
                    float p = __expf(sc[ks][qs][r] - mnew);
                    sum += p;
                    pk[r] = (short)f2bf(p);
                }
                *(bf16x4*)&myPT[(qs * 16 + ln15) * 72 + ks * 16 + quad * 4] = pk;
            }
            sum += __shfl_xor(sum, 16);
            sum += __shfl_xor(sum, 32);
            l_s[qs] = l_s[qs] * alpha + sum;
            m_s[qs] = mnew;
#pragma unroll
            for (int dt = 0; dt < 4; ++dt)
#pragma unroll
                for (int e = 0; e < 4; ++e) o[dt][qs][e] *= alpha;
        }
        // O^T += V^T . P^T  (per-wave PT: same-wave lgkm ordering, no barrier)
        short8 pf[2][2];
#pragma unroll
        for (int qs = 0; qs < 2; ++qs)
#pragma unroll
            for (int kk = 0; kk < 2; ++kk)
                pf[qs][kk] = *(const short8*)&myPT[(qs * 16 + ln15) * 72 + kk * 32 + quad * 8];
#pragma unroll
        for (int dt = 0; dt < 4; ++dt)
#pragma unroll
            for (int kk = 0; kk < 2; ++kk) {
                short8 vf = *(const short8*)&Vts[(dt * 16 + ln15) * 64 + kk * 32 + quad * 8];
#pragma unroll
                for (int qs = 0; qs < 2; ++qs)
                    o[dt][qs] = __builtin_amdgcn_mfma_f32_16x16x32_bf16(vf, pf[qs][kk], o[dt][qs], 0, 0, 0);
            }
    }
    // epilogue: O^T -> LDS (reuse myPT as Ot[32][72]) with 1/l, then coalesced out
#pragma unroll
    for (int qs = 0; qs < 2; ++qs) {
        float inv = 1.f / l_s[qs];
#pragma unroll
        for (int dt = 0; dt < 4; ++dt) {
            bf16x4 pk;
#pragma unroll
            for (int r = 0; r < 4; ++r) pk[r] = (short)f2bf(o[dt][qs][r] * inv);
            *(bf16x4*)&myPT[(qs * 16 + ln15) * 72 + dt * 16 + quad * 4] = pk;
        }
    }
    const int bi = bh >> 4, h = bh & 15;
#pragma unroll
    for (int p = 0; p < 4; ++p) {
        int row = p * 8 + (lane >> 3);         // q within wave tile
        int c8 = (lane & 7) * 8;               // d offset
        short8 vv = *(const short8*)&myPT[row * 72 + c8];
        int qg = qw + row;
        *(short8*)&Aout[((size_t)bi * 2048 + qg) * 1024 + h * 64 + c8] = vv;
    }
}

// ---------------------------------------------------------------------------
// Kernel 4: out(f32) = attn_bf[8192x1024] * WoB^T + bo(f32).
// ---------------------------------------------------------------------------
__global__ __launch_bounds__(256) void outproj_k(const ushort_t* A, const ushort_t* WoB,
                                                 const float* bo, float* Out) {
    __shared__ __align__(16) ushort_t As[128 * 64];
    __shared__ __align__(16) ushort_t Bs[128 * 64];
    const int tid = threadIdx.x, wave = tid >> 6, lane = tid & 63;
    const int ln15 = lane & 15, quad = lane >> 4;
    const int wm = wave >> 1, wn = wave & 1;
    const int lrow = lane >> 3, lcol = (lane & 7) * 8;
    const int m0 = blockIdx.x * 128, n0 = blockIdx.y * 128;

    f32x4 acc[4][4];
#pragma unroll
    for (int i = 0; i < 4; ++i)
#pragma unroll
        for (int j = 0; j < 4; ++j)
#pragma unroll
            for (int e = 0; e < 4; ++e) acc[i][j][e] = 0.f;

    for (int k0 = 0; k0 < 1024; k0 += 64) {
        __syncthreads();
#pragma unroll
        for (int i = 0; i < 4; ++i) {
            int br = i * 32 + wave * 8;
            gl_lds16(A   + (size_t)(m0 + br + lrow) * 1024 + k0 + lcol, &As[br * 64]);
            gl_lds16(WoB + (size_t)(n0 + br + lrow) * 1024 + k0 + lcol, &Bs[br * 64]);
        }
        __syncthreads();
#pragma unroll
        for (int kk = 0; kk < 2; ++kk) {
            short8 a[4], b[4];
#pragma unroll
            for (int f = 0; f < 4; ++f)
                a[f] = *(const short8*)&As[(wm * 64 + f * 16 + ln15) * 64 + kk * 32 + quad * 8];
#pragma unroll
            for (int f = 0; f < 4; ++f)
                b[f] = *(const short8*)&Bs[(wn * 64 + f * 16 + ln15) * 64 + kk * 32 + quad * 8];
#pragma unroll
            for (int fm = 0; fm < 4; ++fm)
#pragma unroll
                for (int fn = 0; fn < 4; ++fn)
                    acc[fm][fn] = __builtin_amdgcn_mfma_f32_16x16x32_bf16(a[fm], b[fn], acc[fm][fn], 0, 0, 0);
        }
    }
#pragma unroll
    for (int fn = 0; fn < 4; ++fn) {
        int n = n0 + wn * 64 + fn * 16 + ln15;
        float bias = bo[n];
#pragma unroll
        for (int fm = 0; fm < 4; ++fm)
#pragma unroll
            for (int r = 0; r < 4; ++r) {
                int mg = m0 + wm * 64 + fm * 16 + quad * 4 + r;
                Out[(size_t)mg * 1024 + n] = acc[fm][fn][r] + bias;
            }
    }
}

// ---------------------------------------------------------------------------
extern "C" void kernel_launch(void* const* d_in, const int* in_sizes, int n_in,
                              void* d_out, int out_size, void* d_ws, size_t ws_size,
                              hipStream_t stream) {
    (void)in_sizes; (void)n_in; (void)out_size; (void)ws_size;
    const float* inp = (const float*)d_in[0];   // [4,2048,1024] f32
    const float* Wq  = (const float*)d_in[1];   // [16,1024,64]  f32
    const float* Wk  = (const float*)d_in[2];
    const float* Wv  = (const float*)d_in[3];
    const float* Wo  = (const float*)d_in[4];   // [1024,1024]   f32
    const float* bo  = (const float*)d_in[5];   // [1024]        f32
    float* out = (float*)d_out;                  // [4,2048,1024] f32

    ushort_t* ws = (ushort_t*)d_ws;
    // R0 (16 MB): inp_bf during kernels 0-2, then At during kernels 3-4
    ushort_t* R0  = ws;                       // 8,388,608 el
    ushort_t* WT  = R0  + 8388608;            // [3][16][64][1024] = 3,145,728 el
    ushort_t* WoB = WT  + 3145728;            // [1024][1024]      = 1,048,576 el
    ushort_t* Qb  = WoB + 1048576;            // [4][16][2048][64] = 8,388,608 el
    ushort_t* Kb  = Qb  + 8388608;            // [4][16][2048][64]
    ushort_t* Vtb = Kb  + 8388608;            // [4][16][64][2048] (transposed V)
    // total ws: 37,748,736 ushorts = 75.5 MB

    ushort_t* inp_bf = R0;
    ushort_t* At     = R0;

    cvt_k<<<4096, 256, 0, stream>>>(inp, inp_bf, 8388608);
    cvt_k<<<512, 256, 0, stream>>>(Wo, WoB, 1048576);
    wtrans_k<<<768, 256, 0, stream>>>(Wq, Wk, Wv, WT);
    qkv_k<<<dim3(32, 48), 256, 0, stream>>>(inp_bf, WT, Qb, Kb, Vtb);
    flash_k<<<dim3(1024), 256, 0, stream>>>(Qb, Kb, Vtb, At);
    outproj_k<<<dim3(64, 8), 256, 0, stream>>>(At, WoB, bo, out);
}

// Round 5
// 280.532 us; speedup vs baseline: 1.9325x; 1.0090x over previous
//
#include <hip/hip_runtime.h>
#include <stdint.h>

typedef unsigned short ushort_t;
typedef __attribute__((ext_vector_type(8))) short short8;
typedef __attribute__((ext_vector_type(4))) short bf16x4;
typedef __attribute__((ext_vector_type(4))) float f32x4;

#define AS1 __attribute__((address_space(1)))
#define AS3 __attribute__((address_space(3)))

// async global->LDS, 16B per lane; LDS dest is wave-uniform base + lane*16
__device__ __forceinline__ void gl_lds16(const void* g, void* l) {
    __builtin_amdgcn_global_load_lds((const AS1 unsigned int*)g,
                                     (AS3 unsigned int*)l, 16, 0, 0);
}

__device__ __forceinline__ ushort_t f2bf(float f) {   // RNE f32 -> bf16
    union { float f; unsigned u; } v; v.f = f;
    unsigned r = v.u + 0x7fffu + ((v.u >> 16) & 1u);
    return (ushort_t)(r >> 16);
}

// ---------------------------------------------------------------------------
// Kernel 0: f32 -> bf16 convert (RNE), 8 elements/thread
// ---------------------------------------------------------------------------
__global__ __launch_bounds__(256) void cvt_k(const float* __restrict__ src,
                                             ushort_t* __restrict__ dst, int n) {
    int i = (blockIdx.x * 256 + threadIdx.x) * 8;
    if (i >= n) return;
    float4 a = *(const float4*)(src + i);
    float4 b = *(const float4*)(src + i + 4);
    short8 o;
    o[0] = (short)f2bf(a.x); o[1] = (short)f2bf(a.y);
    o[2] = (short)f2bf(a.z); o[3] = (short)f2bf(a.w);
    o[4] = (short)f2bf(b.x); o[5] = (short)f2bf(b.y);
    o[6] = (short)f2bf(b.z); o[7] = (short)f2bf(b.w);
    *(short8*)(dst + i) = o;
}

// ---------------------------------------------------------------------------
// Kernel 1: transpose+convert Wq/Wk/Wv (f32) [16][1024][64] -> WT bf16 [3][16][64][1024]
// Flat view: WT row n = mat*1024 + h*64 + d, K-contiguous — the B^T of the
// unified QKV GEMM.
// ---------------------------------------------------------------------------
__global__ __launch_bounds__(256) void wtrans_k(const float* Wq, const float* Wk,
                                                const float* Wv, ushort_t* WT) {
    __shared__ ushort_t t[64 * 65];
    const int bx = blockIdx.x;            // 0..767 : mat(3) x h(16) x etile(16)
    const int mat = bx >> 8;
    const int h   = (bx >> 4) & 15;
    const int et  = bx & 15;
    const float* W = (mat == 0 ? Wq : (mat == 1 ? Wk : Wv)) + h * (1024 * 64);
    const float* src = W + et * 64 * 64;
    const int tid = threadIdx.x;
#pragma unroll
    for (int i = 0; i < 16; ++i) {
        int idx = i * 256 + tid;
        int e = idx >> 6, d = idx & 63;
        t[e * 65 + d] = f2bf(src[idx]);
    }
    __syncthreads();
    ushort_t* dst = WT + (mat * 16 + h) * (64 * 1024) + et * 64;
#pragma unroll
    for (int i = 0; i < 16; ++i) {
        int idx = i * 256 + tid;
        int d = idx >> 6, e = idx & 63;
        dst[d * 1024 + e] = t[e * 65 + d];
    }
}

// ---------------------------------------------------------------------------
// Kernel 2: UNIFIED QKV GEMM. C[8192 x 3072] = inp_bf[8192x1024] * WT^T,
// n = mat*1024 + h*64 + d. m97 128x128 tile, 4 waves 2x2; a 128-N-tile never
// crosses a mat boundary and each wave's 64-col half is one head.
// Epilogue: Q,K -> [B,H,S,64] (Q scaled 1/8); V -> transposed [B,H,64,S].
// ---------------------------------------------------------------------------
__global__ __launch_bounds__(256) void qkv_k(const ushort_t* A, const ushort_t* WT,
                                             ushort_t* Q, ushort_t* K, ushort_t* Vt) {
    __shared__ __align__(16) ushort_t As[128 * 64];   // 16 KB
    __shared__ __align__(16) ushort_t Bs[128 * 64];   // 16 KB
    const int tid = threadIdx.x, wave = tid >> 6, lane = tid & 63;
    const int ln15 = lane & 15, quad = lane >> 4;
    const int wm = wave >> 1, wn = wave & 1;
    const int lrow = lane >> 3, lcol = (lane & 7) * 8;
    const int m0 = blockIdx.x * 128, n0 = blockIdx.y * 128;

    f32x4 acc[4][4];
#pragma unroll
    for (int i = 0; i < 4; ++i)
#pragma unroll
        for (int j = 0; j < 4; ++j)
#pragma unroll
            for (int e = 0; e < 4; ++e) acc[i][j][e] = 0.f;

    for (int k0 = 0; k0 < 1024; k0 += 64) {
        __syncthreads();
#pragma unroll
        for (int i = 0; i < 4; ++i) {
            int br = i * 32 + wave * 8;
            gl_lds16(A  + (size_t)(m0 + br + lrow) * 1024 + k0 + lcol, &As[br * 64]);
            gl_lds16(WT + (size_t)(n0 + br + lrow) * 1024 + k0 + lcol, &Bs[br * 64]);
        }
        __syncthreads();
#pragma unroll
        for (int kk = 0; kk < 2; ++kk) {
            short8 a[4], b[4];
#pragma unroll
            for (int f = 0; f < 4; ++f)
                a[f] = *(const short8*)&As[(wm * 64 + f * 16 + ln15) * 64 + kk * 32 + quad * 8];
#pragma unroll
            for (int f = 0; f < 4; ++f)
                b[f] = *(const short8*)&Bs[(wn * 64 + f * 16 + ln15) * 64 + kk * 32 + quad * 8];
#pragma unroll
            for (int fm = 0; fm < 4; ++fm)
#pragma unroll
                for (int fn = 0; fn < 4; ++fn)
                    acc[fm][fn] = __builtin_amdgcn_mfma_f32_16x16x32_bf16(a[fm], b[fn], acc[fm][fn], 0, 0, 0);
        }
    }
    const int n_base = n0 + wn * 64;          // this wave's 64-col head block
    const int mat = n_base >> 10;             // 0:Q 1:K 2:V (uniform per wave)
    const int h   = (n_base >> 6) & 15;
    if (mat < 2) {
        ushort_t* dst = (mat == 0) ? Q : K;
        const float scale = (mat == 0) ? 0.125f : 1.0f;   // 1/sqrt(64) into Q
#pragma unroll
        for (int fm = 0; fm < 4; ++fm) {
#pragma unroll
            for (int r = 0; r < 4; ++r) {
                int mg = m0 + wm * 64 + fm * 16 + quad * 4 + r;
                int bi = mg >> 11, s = mg & 2047;
                size_t base = ((size_t)(bi * 16 + h) * 2048 + s) * 64;
#pragma unroll
                for (int fn = 0; fn < 4; ++fn)
                    dst[base + fn * 16 + ln15] = f2bf(acc[fm][fn][r] * scale);
            }
        }
    } else {
        // V transposed: Vt[b][h][d][s]
#pragma unroll
        for (int fm = 0; fm < 4; ++fm) {
#pragma unroll
            for (int r = 0; r < 4; ++r) {
                int mg = m0 + wm * 64 + fm * 16 + quad * 4 + r;
                int bi = mg >> 11, s = mg & 2047;
#pragma unroll
                for (int fn = 0; fn < 4; ++fn) {
                    int d = fn * 16 + ln15;
                    Vt[((size_t)(bi * 16 + h) * 64 + d) * 2048 + s] = f2bf(acc[fm][fn][r]);
                }
            }
        }
    }
}

// ---------------------------------------------------------------------------
// Kernel 3: causal flash attention, S^T formulation.
// Block = 4 waves, q-tile 128 (32 q/wave). Per 64-key tile:
//   S^T = K·Q^T (C: row=key=quad*4+r, col=q=ln15) -> softmax state is per-lane
//   (2 shfls instead of 32), P^T packed to LDS via b64, O^T = V^T·P^T.
// Grid ordered big-qt-first for load balance; fully-masked waves skip compute.
// ---------------------------------------------------------------------------
__global__ __launch_bounds__(256, 3) void flash_k(const ushort_t* Q, const ushort_t* K,
                                                  const ushort_t* Vt, ushort_t* Aout) {
    __shared__ __align__(16) ushort_t Qs[128 * 64];    // 16 KB
    __shared__ __align__(16) ushort_t Ks[64 * 64];     //  8 KB
    __shared__ __align__(16) ushort_t Vts[64 * 64];    //  8 KB
    __shared__ __align__(16) ushort_t PT[4][32 * 72];  // 18 KB, per-wave P^T[q][key]
    const int tid = threadIdx.x, wave = tid >> 6, lane = tid & 63;
    const int ln15 = lane & 15, quad = lane >> 4;
    const int bx = blockIdx.x;
    const int qt = 15 - (bx >> 6);             // big tiles dispatch first
    const int bh = bx & 63;
    const int q0 = qt * 128;
    const int qw = q0 + wave * 32;             // this wave's first q row
    const ushort_t* Qb = Q + ((size_t)bh * 2048 + q0) * 64;
    const ushort_t* Kb = K + (size_t)bh * 2048 * 64;
    const ushort_t* Vb = Vt + (size_t)bh * 64 * 2048;
    ushort_t* myPT = PT[wave];

    // stage Q tile 128x64
    {
        int c8 = (tid & 7) * 8;
#pragma unroll
        for (int i = 0; i < 4; ++i) {
            int row = i * 32 + (tid >> 3);
            gl_lds16(Qb + (size_t)row * 64 + c8, &Qs[row * 64 + c8]);
        }
    }
    __syncthreads();
    short8 qf[2][2];
#pragma unroll
    for (int qs = 0; qs < 2; ++qs)
#pragma unroll
        for (int kk = 0; kk < 2; ++kk)
            qf[qs][kk] = *(const short8*)&Qs[(wave * 32 + qs * 16 + ln15) * 64 + kk * 32 + quad * 8];

    f32x4 o[4][2];
#pragma unroll
    for (int dt = 0; dt < 4; ++dt)
#pragma unroll
        for (int qs = 0; qs < 2; ++qs)
#pragma unroll
            for (int e = 0; e < 4; ++e) o[dt][qs][e] = 0.f;
    float m_s[2] = {-1e30f, -1e30f}, l_s[2] = {0.f, 0.f};

    const int ktEnd = 2 * qt + 2;
    for (int kt = 0; kt < ktEnd; ++kt) {
        __syncthreads();   // prior reads of Ks/Vts complete
        {
            int row = tid >> 3, c8 = (tid & 7) * 8;
            gl_lds16(Kb + (size_t)(kt * 64 + row) * 64 + c8,      &Ks[row * 64 + c8]);
            gl_lds16(Kb + (size_t)(kt * 64 + 32 + row) * 64 + c8, &Ks[(32 + row) * 64 + c8]);
            gl_lds16(Vb + (size_t)row * 2048 + kt * 64 + c8,        &Vts[row * 64 + c8]);
            gl_lds16(Vb + (size_t)(32 + row) * 2048 + kt * 64 + c8, &Vts[(32 + row) * 64 + c8]);
        }
        __syncthreads();
        if (kt * 64 > qw + 31) continue;       // wave fully masked (uniform)

        // S^T = K . Q^T
        f32x4 sc[4][2];
#pragma unroll
        for (int ks = 0; ks < 4; ++ks) {
#pragma unroll
            for (int qs = 0; qs < 2; ++qs)
#pragma unroll
                for (int e = 0; e < 4; ++e) sc[ks][qs][e] = 0.f;
#pragma unroll
            for (int kk = 0; kk < 2; ++kk) {
                short8 kf = *(const short8*)&Ks[(ks * 16 + ln15) * 64 + kk * 32 + quad * 8];
#pragma unroll
                for (int qs = 0; qs < 2; ++qs)
                    sc[ks][qs] = __builtin_amdgcn_mfma_f32_16x16x32_bf16(kf, qf[qs][kk], sc[ks][qs], 0, 0, 0);
            }
        }
        if (kt * 64 + 63 > qw) {               // diagonal: causal mask
#pragma unroll
            for (int ks = 0; ks < 4; ++ks)
#pragma unroll
                for (int qs = 0; qs < 2; ++qs) {
                    int qg = qw + qs * 16 + ln15;
#pragma unroll
                    for (int r = 0; r < 4; ++r) {
                        int kg = kt * 64 + ks * 16 + quad * 4 + r;
                        if (kg > qg) sc[ks][qs][r] = -1e30f;
                    }
                }
        }
        // online softmax: per-lane state (col q = ln15), reduce across quads only
#pragma unroll
        for (int qs = 0; qs < 2; ++qs) {
            float mx = sc[0][qs][0];
#pragma unroll
            for (int ks = 0; ks < 4; ++ks)
#pragma unroll
                for (int r = 0; r < 4; ++r) mx = fmaxf(mx, sc[ks][qs][r]);
            mx = fmaxf(mx, __shfl_xor(mx, 16));
            mx = fmaxf(mx, __shfl_xor(mx, 32));
            float mnew = fmaxf(m_s[qs], mx);
            float alpha = __expf(m_s[qs] - mnew);
            float sum = 0.f;
#pragma unroll
            for (int ks = 0; ks < 4; ++ks) {
                bf16x4 pk;
#pragma unroll
                for (int r = 0; r < 4; ++r) {
                    float p = __expf(sc[ks][qs][r] - mnew);
                    sum += p;
                    pk[r] = (short)f2bf(p);
                }
                *(bf16x4*)&myPT[(qs * 16 + ln15) * 72 + ks * 16 + quad * 4] = pk;
            }
            sum += __shfl_xor(sum, 16);
            sum += __shfl_xor(sum, 32);
            l_s[qs] = l_s[qs] * alpha + sum;
            m_s[qs] = mnew;
#pragma unroll
            for (int dt = 0; dt < 4; ++dt)
#pragma unroll
                for (int e = 0; e < 4; ++e) o[dt][qs][e] *= alpha;
        }
        // O^T += V^T . P^T  (per-wave PT: same-wave lgkm ordering, no barrier)
        short8 pf[2][2];
#pragma unroll
        for (int qs = 0; qs < 2; ++qs)
#pragma unroll
            for (int kk = 0; kk < 2; ++kk)
                pf[qs][kk] = *(const short8*)&myPT[(qs * 16 + ln15) * 72 + kk * 32 + quad * 8];
#pragma unroll
        for (int dt = 0; dt < 4; ++dt)
#pragma unroll
            for (int kk = 0; kk < 2; ++kk) {
                short8 vf = *(const short8*)&Vts[(dt * 16 + ln15) * 64 + kk * 32 + quad * 8];
#pragma unroll
                for (int qs = 0; qs < 2; ++qs)
                    o[dt][qs] = __builtin_amdgcn_mfma_f32_16x16x32_bf16(vf, pf[qs][kk], o[dt][qs], 0, 0, 0);
            }
    }
    // epilogue: O^T -> LDS (reuse myPT as Ot[32][72]) with 1/l, then coalesced out
#pragma unroll
    for (int qs = 0; qs < 2; ++qs) {
        float inv = 1.f / l_s[qs];
#pragma unroll
        for (int dt = 0; dt < 4; ++dt) {
            bf16x4 pk;
#pragma unroll
            for (int r = 0; r < 4; ++r) pk[r] = (short)f2bf(o[dt][qs][r] * inv);
            *(bf16x4*)&myPT[(qs * 16 + ln15) * 72 + dt * 16 + quad * 4] = pk;
        }
    }
    const int bi = bh >> 4, h = bh & 15;
#pragma unroll
    for (int p = 0; p < 4; ++p) {
        int row = p * 8 + (lane >> 3);         // q within wave tile
        int c8 = (lane & 7) * 8;               // d offset
        short8 vv = *(const short8*)&myPT[row * 72 + c8];
        int qg = qw + row;
        *(short8*)&Aout[((size_t)bi * 2048 + qg) * 1024 + h * 64 + c8] = vv;
    }
}

// ---------------------------------------------------------------------------
// Kernel 4: out(f32) = attn_bf[8192x1024] * WoB^T + bo(f32).
// ---------------------------------------------------------------------------
__global__ __launch_bounds__(256) void outproj_k(const ushort_t* A, const ushort_t* WoB,
                                                 const float* bo, float* Out) {
    __shared__ __align__(16) ushort_t As[128 * 64];
    __shared__ __align__(16) ushort_t Bs[128 * 64];
    const int tid = threadIdx.x, wave = tid >> 6, lane = tid & 63;
    const int ln15 = lane & 15, quad = lane >> 4;
    const int wm = wave >> 1, wn = wave & 1;
    const int lrow = lane >> 3, lcol = (lane & 7) * 8;
    const int m0 = blockIdx.x * 128, n0 = blockIdx.y * 128;

    f32x4 acc[4][4];
#pragma unroll
    for (int i = 0; i < 4; ++i)
#pragma unroll
        for (int j = 0; j < 4; ++j)
#pragma unroll
            for (int e = 0; e < 4; ++e) acc[i][j][e] = 0.f;

    for (int k0 = 0; k0 < 1024; k0 += 64) {
        __syncthreads();
#pragma unroll
        for (int i = 0; i < 4; ++i) {
            int br = i * 32 + wave * 8;
            gl_lds16(A   + (size_t)(m0 + br + lrow) * 1024 + k0 + lcol, &As[br * 64]);
            gl_lds16(WoB + (size_t)(n0 + br + lrow) * 1024 + k0 + lcol, &Bs[br * 64]);
        }
        __syncthreads();
#pragma unroll
        for (int kk = 0; kk < 2; ++kk) {
            short8 a[4], b[4];
#pragma unroll
            for (int f = 0; f < 4; ++f)
                a[f] = *(const short8*)&As[(wm * 64 + f * 16 + ln15) * 64 + kk * 32 + quad * 8];
#pragma unroll
            for (int f = 0; f < 4; ++f)
                b[f] = *(const short8*)&Bs[(wn * 64 + f * 16 + ln15) * 64 + kk * 32 + quad * 8];
#pragma unroll
            for (int fm = 0; fm < 4; ++fm)
#pragma unroll
                for (int fn = 0; fn < 4; ++fn)
                    acc[fm][fn] = __builtin_amdgcn_mfma_f32_16x16x32_bf16(a[fm], b[fn], acc[fm][fn], 0, 0, 0);
        }
    }
#pragma unroll
    for (int fn = 0; fn < 4; ++fn) {
        int n = n0 + wn * 64 + fn * 16 + ln15;
        float bias = bo[n];
#pragma unroll
        for (int fm = 0; fm < 4; ++fm)
#pragma unroll
            for (int r = 0; r < 4; ++r) {
                int mg = m0 + wm * 64 + fm * 16 + quad * 4 + r;
                Out[(size_t)mg * 1024 + n] = acc[fm][fn][r] + bias;
            }
    }
}

// ---------------------------------------------------------------------------
extern "C" void kernel_launch(void* const* d_in, const int* in_sizes, int n_in,
                              void* d_out, int out_size, void* d_ws, size_t ws_size,
                              hipStream_t stream) {
    (void)in_sizes; (void)n_in; (void)out_size; (void)ws_size;
    const float* inp = (const float*)d_in[0];   // [4,2048,1024] f32
    const float* Wq  = (const float*)d_in[1];   // [16,1024,64]  f32
    const float* Wk  = (const float*)d_in[2];
    const float* Wv  = (const float*)d_in[3];
    const float* Wo  = (const float*)d_in[4];   // [1024,1024]   f32
    const float* bo  = (const float*)d_in[5];   // [1024]        f32
    float* out = (float*)d_out;                  // [4,2048,1024] f32

    ushort_t* ws = (ushort_t*)d_ws;
    // R0 (16 MB): inp_bf during kernels 0-2, then At during kernels 3-4
    ushort_t* R0  = ws;                       // 8,388,608 el
    ushort_t* WT  = R0  + 8388608;            // [3][16][64][1024] = 3,145,728 el
    ushort_t* WoB = WT  + 3145728;            // [1024][1024]      = 1,048,576 el
    ushort_t* Qb  = WoB + 1048576;            // [4][16][2048][64] = 8,388,608 el
    ushort_t* Kb  = Qb  + 8388608;            // [4][16][2048][64]
    ushort_t* Vtb = Kb  + 8388608;            // [4][16][64][2048] (transposed V)
    // total ws: 37,748,736 ushorts = 75.5 MB

    ushort_t* inp_bf = R0;
    ushort_t* At     = R0;

    cvt_k<<<4096, 256, 0, stream>>>(inp, inp_bf, 8388608);
    cvt_k<<<512, 256, 0, stream>>>(Wo, WoB, 1048576);
    wtrans_k<<<768, 256, 0, stream>>>(Wq, Wk, Wv, WT);
    qkv_k<<<dim3(64, 24), 256, 0, stream>>>(inp_bf, WT, Qb, Kb, Vtb);
    flash_k<<<dim3(1024), 256, 0, stream>>>(Qb, Kb, Vtb, At);
    outproj_k<<<dim3(64, 8), 256, 0, stream>>>(At, WoB, bo, out);
}